// Round 7
// baseline (721.521 us; speedup 1.0000x reference)
//
#include <hip/hip_runtime.h>
#include <hip/hip_bf16.h>

// Qwen3 MoE sparse block, MI355X/gfx950.
// Shapes: T=4096 tokens (B2 x S2048), H=2048, I=768, E=16, top-k=8.
// Round 7: gateup ported to a 4-phase interleaved schedule (T3/T4/T5):
// BM=256 x BN=128 (gate64+up64 paired via interleaved stacked B^T layout),
// BK=32, 4 waves, per-wave 128x64. A 3-buf (lookahead 2), B 2-buf
// (lookahead 1), LDS 64KB, vmcnt(4) + 1 barrier per K-tile, stage issues
// interleaved between MFMA clusters, setprio around MFMA. Epilogue pairs
// gate/up waves through a 32KB LDS exchange, fusing silu*u*w -> hsC.
// Down projection unchanged from r6 (sparse per-expert + slot scatter).

typedef __attribute__((ext_vector_type(8))) short short8;   // 8 x bf16 (4 VGPRs) MFMA operand
typedef __attribute__((ext_vector_type(4))) float f32x4;    // MFMA accumulator

#define NUM_T 4096
#define DH    2048
#define DI    768
#define NE    16
#define DKD   (NE*DI)        // 12288 (dense wdbt row length)
#define HSC_CAP 2560         // compacted rows capacity per expert
#define TOK_HALF 2048
#define GU_NT (DH/32)        // 64 K-tiles in gateup
#define FINAL_ELEMS ((size_t)NUM_T*DH)

// ---- helpers -------------------------------------------------------------

static __device__ __forceinline__ unsigned short f2bf(float f) {
  unsigned int u = __builtin_bit_cast(unsigned int, f);
  u += 0x7fffu + ((u >> 16) & 1u);
  return (unsigned short)(u >> 16);
}

static __device__ __forceinline__ float bf2f(unsigned short b) {
  unsigned int u = ((unsigned int)b) << 16;
  return __builtin_bit_cast(float, u);
}

static __device__ __forceinline__ void gload16(const void* g, void* l) {
  __builtin_amdgcn_global_load_lds(
      (__attribute__((address_space(1))) void*)(g),
      (__attribute__((address_space(3))) void*)(l), 16, 0, 0);
}

// ---- kernel 1: hidden fp32 -> bf16 --------------------------------------

__global__ __launch_bounds__(256)
void cvt_hidden_k(const float* __restrict__ in, unsigned short* __restrict__ out) {
  size_t i = (size_t)blockIdx.x * 256 + threadIdx.x;
  const float4* p = (const float4*)in + i * 2;
  float4 a = p[0], b = p[1];
  short8 v;
  v[0] = (short)f2bf(a.x); v[1] = (short)f2bf(a.y);
  v[2] = (short)f2bf(a.z); v[3] = (short)f2bf(a.w);
  v[4] = (short)f2bf(b.x); v[5] = (short)f2bf(b.y);
  v[6] = (short)f2bf(b.z); v[7] = (short)f2bf(b.w);
  *(short8*)(out + i * 8) = v;
}

// ---- kernel 2: transpose + convert with output-row remap -----------------
// out row for original B^T row r (= input col): s = (r>>rShift)*rStrd + rOff
// + (r & ((1<<rShift)-1)). Used to build the gate/up-interleaved stacked B^T.

__global__ __launch_bounds__(256)
void transpose_cvt_k(const float* __restrict__ in, unsigned short* __restrict__ out,
                     int C, long inStrideE, long outStrideE, int outLD,
                     int rShift, int rStrd, int rOff) {
  __shared__ float tile[32][33];
  const float* inE = in + (size_t)blockIdx.z * inStrideE;
  unsigned short* outE = out + (size_t)blockIdx.z * outStrideE;
  int c0 = blockIdx.x * 32, r0 = blockIdx.y * 32;
  int tx = threadIdx.x, ty = threadIdx.y;
#pragma unroll
  for (int i = 0; i < 4; i++)
    tile[ty * 4 + i][tx] = inE[(size_t)(r0 + ty * 4 + i) * C + c0 + tx];
  __syncthreads();
#pragma unroll
  for (int i = 0; i < 4; i++) {
    int c = ty * 4 + i;
    int r = c0 + c;                                   // original B^T row
    int s = ((r >> rShift) * rStrd) + rOff + (r & ((1 << rShift) - 1));
    outE[(size_t)s * outLD + r0 + tx] = f2bf(tile[tx][c]);
  }
}

// ---- kernel 3: router + softmax + top-8 + renorm + slot assignment ------

__global__ __launch_bounds__(256)
void router_k(const float* __restrict__ x, const float* __restrict__ wr,
              float* __restrict__ logits_out, unsigned short* __restrict__ dwb,
              unsigned char* __restrict__ slt) {
  int t = blockIdx.x;
  int tid = threadIdx.x, lane = tid & 63, wid = tid >> 6;
  float acc[16];
#pragma unroll
  for (int e = 0; e < 16; e++) acc[e] = 0.f;
  const float* xt = x + (size_t)t * DH;
  for (int i = tid; i < DH; i += 256) {
    float hv = xt[i];
    const float4* w4 = (const float4*)(wr + (size_t)i * 16);
#pragma unroll
    for (int q = 0; q < 4; q++) {
      float4 w = w4[q];
      acc[q * 4 + 0] += hv * w.x; acc[q * 4 + 1] += hv * w.y;
      acc[q * 4 + 2] += hv * w.z; acc[q * 4 + 3] += hv * w.w;
    }
  }
#pragma unroll
  for (int e = 0; e < 16; e++) {
#pragma unroll
    for (int off = 32; off; off >>= 1) acc[e] += __shfl_xor(acc[e], off, 64);
  }
  __shared__ float red[4][16];
  if (lane == 0) {
#pragma unroll
    for (int e = 0; e < 16; e++) red[wid][e] = acc[e];
  }
  __syncthreads();
  if (tid == 0) {
    float lg[16];
#pragma unroll
    for (int e = 0; e < 16; e++) lg[e] = red[0][e] + red[1][e] + red[2][e] + red[3][e];
    float mx = lg[0];
#pragma unroll
    for (int e = 1; e < 16; e++) mx = fmaxf(mx, lg[e]);
    float p[16], s = 0.f;
#pragma unroll
    for (int e = 0; e < 16; e++) { p[e] = __expf(lg[e] - mx); s += p[e]; }
    float inv = 1.f / s;
#pragma unroll
    for (int e = 0; e < 16; e++) p[e] *= inv;
    float tmp[16];
#pragma unroll
    for (int e = 0; e < 16; e++) tmp[e] = p[e];
    int idx[8]; float val[8]; float ts = 0.f;
#pragma unroll
    for (int k = 0; k < 8; k++) {
      int b = 0; float bv = tmp[0];
#pragma unroll
      for (int e = 1; e < 16; e++) { if (tmp[e] > bv) { bv = tmp[e]; b = e; } }
      idx[k] = b; val[k] = bv; tmp[b] = -1.f; ts += bv;
    }
    float dw[16];
    unsigned char sl[16];
#pragma unroll
    for (int e = 0; e < 16; e++) { dw[e] = 0.f; sl[e] = 0xFF; }
    float invt = 1.f / ts;
#pragma unroll
    for (int k = 0; k < 8; k++) { dw[idx[k]] += val[k] * invt; sl[idx[k]] = (unsigned char)k; }
#pragma unroll
    for (int e = 0; e < 16; e++) {
      dwb[(size_t)t * 16 + e] = f2bf(dw[e]);
      slt[(size_t)t * 16 + e] = sl[e];
      logits_out[(size_t)t * 16 + e] = lg[e];
    }
  }
}

// ---- kernel 3b: per-expert compacted token lists + split metadata -------

__global__ __launch_bounds__(256)
void build_lists_k(const unsigned short* __restrict__ dwb,
                   const unsigned char* __restrict__ slt,
                   unsigned short* __restrict__ lst, int* __restrict__ meta) {
  int e = blockIdx.x;
  int tid = threadIdx.x;
  unsigned short loc[16]; int c = 0;
#pragma unroll
  for (int j = 0; j < 16; j++) {
    int t = tid * 16 + j;
    if (dwb[(size_t)t * 16 + e] != 0) {
      unsigned short s = slt[(size_t)t * 16 + e];
      loc[c++] = (unsigned short)(t | (s << 12));
    }
  }
  __shared__ int sc[256];
  __shared__ int pre[257];
  sc[tid] = c;
  __syncthreads();
  if (tid == 0) {
    int s = 0;
    for (int i = 0; i < 256; i++) { pre[i] = s; s += sc[i]; }
    pre[256] = s;
  }
  __syncthreads();
  unsigned short* L = lst + (size_t)e * NUM_T;
  int base = pre[tid];
  for (int j = 0; j < c; j++) L[base + j] = loc[j];
  int total = pre[256];
  for (int i = total + tid; i < NUM_T; i += 256) L[i] = 0xFFFFu;
  if (tid == 0) { meta[e * 2] = pre[128]; meta[e * 2 + 1] = total; }
}

// ---- kernel 4: gateup, 4-phase interleaved schedule ----------------------
// Tile 256 tokens x 128 stacked cols (gate64 | up64), BK=32, 4 waves 2Mx2N,
// per-wave C = 128x64 (acc[8][4]). A 3-buf / B 2-buf LDS (64KB), vmcnt(4)
// + one barrier per K-tile, stages interleaved between 8-MFMA clusters.

__global__ __launch_bounds__(256, 2)
void gateup_k(const unsigned short* __restrict__ hbf,
              const unsigned short* __restrict__ wgubt,
              const unsigned short* __restrict__ dwb,
              const unsigned short* __restrict__ lst,
              unsigned short* __restrict__ hsC) {
  // XCD-bijective swizzle: 1920 = 8 * 240; e-major -> n-tile -> m-tile
  const int bxr = blockIdx.x;
  const int wl  = (bxr & 7) * 240 + (bxr >> 3);
  const int e   = wl / 120;                 // 120 = 12 n-tiles * 10 m-tiles
  const int rem = wl - e * 120;
  const int j   = rem / 10;                 // n-tile: gate cols [j*64, j*64+64)
  const int m0  = (rem % 10) * 256;

  const unsigned short* L = lst + (size_t)e * NUM_T;
  if (L[m0] & 0x8000) return;               // tile fully beyond count[e]

  const int tid = threadIdx.x, lane = tid & 63, wid = tid >> 6;
  const int wr = wid >> 1, wc = wid & 1;
  const int lr = lane & 15, lgp = lane >> 4;

  __shared__ alignas(16) unsigned short ALDS[3 * 256 * 32];  // 48KB, A 3-buf
  __shared__ alignas(16) unsigned short BLDS[2 * 128 * 32];  // 16KB, B 2-buf

  f32x4 zero = {0.f, 0.f, 0.f, 0.f};
  f32x4 acc[8][4];
#pragma unroll
  for (int m = 0; m < 8; m++)
#pragma unroll
    for (int n = 0; n < 4; n++) acc[m][n] = zero;

  const unsigned short* wgubtE = wgubt + (size_t)e * 1536 * DH;

  const int srow    = lane >> 2;                                   // 0..15
  const int schunk8 = (((lane & 3) - ((lane >> 3) & 3)) & 3) * 8;  // inverse swizzle, src
  const int slot8   = (((lane >> 4) + ((lane >> 1) & 3)) & 3) * 8; // fragment read slot

  // A gather: wave stages token rows [wid*64, +64) as 4 gload16
  const unsigned short* gA[4];
#pragma unroll
  for (int i = 0; i < 4; i++) {
    unsigned short en = L[m0 + wid * 64 + i * 16 + srow];
    size_t tok = (en & 0x8000) ? 0 : (size_t)(en & 0xFFF);
    gA[i] = hbf + tok * DH + schunk8;
  }
  // B: wave stages stacked rows [j*128 + wid*32, +32) as 2 gload16
  const unsigned short* gB[2];
#pragma unroll
  for (int i = 0; i < 2; i++)
    gB[i] = wgubtE + ((size_t)j * 128 + wid * 32 + i * 16 + srow) * DH + schunk8;

#define STAGE_A(buf, t, i) gload16(gA[i] + (size_t)(t) * 32, \
    ALDS + (buf) * 8192 + (wid * 64 + (i) * 16) * 32)
#define STAGE_B(buf, t, i) gload16(gB[i] + (size_t)(t) * 32, \
    BLDS + (buf) * 4096 + (wid * 32 + (i) * 16) * 32)
#define RD_A(mf) (*(const short8*)(Ab + (wr * 128 + (mf) * 16 + lr) * 32 + slot8))
#define RD_B(nf) (*(const short8*)(Bb + (wc * 64 + (nf) * 16 + lr) * 32 + slot8))
#define MFMA4(m0_, m1_, m2_, m3_, n_) \
    acc[m0_][n_] = __builtin_amdgcn_mfma_f32_16x16x32_bf16(a[m0_], b[n_], acc[m0_][n_], 0, 0, 0); \
    acc[m1_][n_] = __builtin_amdgcn_mfma_f32_16x16x32_bf16(a[m1_], b[n_], acc[m1_][n_], 0, 0, 0); \
    acc[m2_][n_] = __builtin_amdgcn_mfma_f32_16x16x32_bf16(a[m2_], b[n_], acc[m2_][n_], 0, 0, 0); \
    acc[m3_][n_] = __builtin_amdgcn_mfma_f32_16x16x32_bf16(a[m3_], b[n_], acc[m3_][n_], 0, 0, 0);

  // prologue: B(0), A(0), A(1) — oldest-first so vmcnt(4) leaves only A(1)
  STAGE_B(0, 0, 0); STAGE_B(0, 0, 1);
  STAGE_A(0, 0, 0); STAGE_A(0, 0, 1); STAGE_A(0, 0, 2); STAGE_A(0, 0, 3);
  STAGE_A(1, 1, 0); STAGE_A(1, 1, 1); STAGE_A(1, 1, 2); STAGE_A(1, 1, 3);

  int ra = 0, rb = 0, sa = 2;
  short8 a[8], b[4];
#pragma unroll 1
  for (int t = 0; t < GU_NT; ++t) {
    // tile-t data guaranteed complete; newest 4 outstanding = A(t+1) stages
    if (t < GU_NT - 1) asm volatile("s_waitcnt vmcnt(4)" ::: "memory");
    else               asm volatile("s_waitcnt vmcnt(0)" ::: "memory");
    __builtin_amdgcn_s_barrier();
    __builtin_amdgcn_sched_barrier(0);
    const unsigned short* Ab = ALDS + ra * 8192;
    const unsigned short* Bb = BLDS + rb * 4096;
    // P1: stage B(t+1) || read a0-3, b0-1 || mfma m0-3 x n0-1
    if (t + 1 < GU_NT) { STAGE_B(rb ^ 1, t + 1, 0); STAGE_B(rb ^ 1, t + 1, 1); }
    a[0] = RD_A(0); a[1] = RD_A(1); a[2] = RD_A(2); a[3] = RD_A(3);
    b[0] = RD_B(0); b[1] = RD_B(1);
    asm volatile("s_waitcnt lgkmcnt(0)" ::: "memory");
    __builtin_amdgcn_sched_barrier(0);
    __builtin_amdgcn_s_setprio(1);
    MFMA4(0, 1, 2, 3, 0); MFMA4(0, 1, 2, 3, 1);
    __builtin_amdgcn_s_setprio(0);
    // P2: stage A(t+2) half || read a4-7 || mfma m4-7 x n0-1
    if (t + 2 < GU_NT) { STAGE_A(sa, t + 2, 0); STAGE_A(sa, t + 2, 1); }
    a[4] = RD_A(4); a[5] = RD_A(5); a[6] = RD_A(6); a[7] = RD_A(7);
    asm volatile("s_waitcnt lgkmcnt(0)" ::: "memory");
    __builtin_amdgcn_sched_barrier(0);
    __builtin_amdgcn_s_setprio(1);
    MFMA4(4, 5, 6, 7, 0); MFMA4(4, 5, 6, 7, 1);
    __builtin_amdgcn_s_setprio(0);
    // P3: stage A(t+2) half || read b2-3 || mfma m4-7 x n2-3
    if (t + 2 < GU_NT) { STAGE_A(sa, t + 2, 2); STAGE_A(sa, t + 2, 3); }
    b[2] = RD_B(2); b[3] = RD_B(3);
    asm volatile("s_waitcnt lgkmcnt(0)" ::: "memory");
    __builtin_amdgcn_sched_barrier(0);
    __builtin_amdgcn_s_setprio(1);
    MFMA4(4, 5, 6, 7, 2); MFMA4(4, 5, 6, 7, 3);
    __builtin_amdgcn_s_setprio(0);
    // P4: mfma m0-3 x n2-3 (a0-3, b2-3 live)
    __builtin_amdgcn_s_setprio(1);
    MFMA4(0, 1, 2, 3, 2); MFMA4(0, 1, 2, 3, 3);
    __builtin_amdgcn_s_setprio(0);
    ra = (ra == 2) ? 0 : ra + 1;
    sa = (sa == 2) ? 0 : sa + 1;
    rb ^= 1;
  }
#undef STAGE_A
#undef STAGE_B
#undef RD_A
#undef RD_B
#undef MFMA4

  // epilogue: up-waves (wc=1) exchange acc via LDS; gate-waves fuse silu*u*w
  __syncthreads();
  unsigned short (*exch)[64] = (unsigned short(*)[64])ALDS;   // 256x64 bf16, 32KB
  if (wc == 1) {
#pragma unroll
    for (int mf = 0; mf < 8; mf++)
#pragma unroll
      for (int nf = 0; nf < 4; nf++)
#pragma unroll
        for (int r = 0; r < 4; r++)
          exch[wr * 128 + mf * 16 + lgp * 4 + r][nf * 16 + lr] = f2bf(acc[mf][nf][r]);
  }
  __syncthreads();
  if (wc == 0) {
#pragma unroll
    for (int mf = 0; mf < 8; mf++) {
#pragma unroll
      for (int r = 0; r < 4; r++) {
        int m = wr * 128 + mf * 16 + lgp * 4 + r;
        unsigned short en = L[m0 + m];
        if (en & 0x8000) continue;
        int tp = en & 0xFFF;
        float w = bf2f(dwb[(size_t)tp * 16 + e]);
#pragma unroll
        for (int nf = 0; nf < 4; nf++) {
          float g = acc[mf][nf][r];
          float u = bf2f(exch[m][nf * 16 + lr]);
          float sig = 1.f / (1.f + __expf(-g));
          hsC[((size_t)e * HSC_CAP + m0 + m) * DI + j * 64 + nf * 16 + lr]
              = f2bf(sig * g * u * w);
        }
      }
    }
  }
}

// ---- kernel 5: per-expert down GEMM (half of tokens) -> slot buffer -----
// Unchanged from round 6 (3-stage counted-vmcnt pipeline).

__global__ __launch_bounds__(256, 3)
void down_half_k(const unsigned short* __restrict__ hsC,
                 const unsigned short* __restrict__ wdbt,
                 const unsigned short* __restrict__ lst,
                 const int* __restrict__ meta,
                 unsigned short* __restrict__ slotbuf, int hf) {
  const int bxr = blockIdx.x;
  const int wl  = (bxr & 7) * 320 + (bxr >> 3);
  const int e   = wl / 160;                 // 160 = 16 n-groups * 10 m-tiles
  const int rem = wl - e * 160;
  const int n0  = (rem / 10) * 128;
  const int m0  = (rem % 10) * 128;

  const int rs = hf ? meta[e * 2] : 0;
  const int re = hf ? meta[e * 2 + 1] : meta[e * 2];
  const int rcount = re - rs;
  if (m0 >= rcount) return;

  const int tid = threadIdx.x, lane = tid & 63, wid = tid >> 6;
  const int wm = wid >> 1, wn = wid & 1;
  const int lr = lane & 15, lgp = lane >> 4;

  __shared__ alignas(16) unsigned short As[3 * 128 * 32];
  __shared__ alignas(16) unsigned short Bs[3 * 128 * 32];

  f32x4 zero = {0.f, 0.f, 0.f, 0.f};
  f32x4 acc[4][4];
#pragma unroll
  for (int m = 0; m < 4; m++)
#pragma unroll
    for (int n = 0; n < 4; n++) acc[m][n] = zero;

  const int srow    = lane >> 2;
  const int schunk8 = (((lane & 3) - ((lane >> 3) & 3)) & 3) * 8;
  const int sOff0   = wid * 1024;
  const int sOff1   = sOff0 + 512;
  const size_t arow0 = (size_t)(e * HSC_CAP + rs + m0 + wid * 32 + srow);
  const size_t arow1 = arow0 + 16;
  const size_t brow0 = (size_t)(n0 + wid * 32 + srow), brow1 = brow0 + 16;
  const int slot8 = (((lane >> 4) + ((lane >> 1) & 3)) & 3) * 8;

  const unsigned short* wdE = wdbt + (size_t)e * DI;

  auto stage = [&](int b, int k0) {
    unsigned short* Ab = As + b * 4096;
    unsigned short* Bb = Bs + b * 4096;
    gload16(hsC + arow0 * DI + k0 + schunk8, Ab + sOff0);
    gload16(hsC + arow1 * DI + k0 + schunk8, Ab + sOff1);
    gload16(wdE + brow0 * DKD + k0 + schunk8, Bb + sOff0);
    gload16(wdE + brow1 * DKD + k0 + schunk8, Bb + sOff1);
  };

  auto compute = [&](int bsel) {
    const unsigned short* Ab = As + bsel * 4096;
    const unsigned short* Bb = Bs + bsel * 4096;
    short8 a[4], b[4];
#pragma unroll
    for (int m = 0; m < 4; m++)
      a[m] = *(const short8*)(Ab + (size_t)(wm * 64 + m * 16 + lr) * 32 + slot8);
#pragma unroll
    for (int n = 0; n < 4; n++)
      b[n] = *(const short8*)(Bb + (size_t)(wn * 64 + n * 16 + lr) * 32 + slot8);
#pragma unroll
    for (int m = 0; m < 4; m++)
#pragma unroll
      for (int n = 0; n < 4; n++)
        acc[m][n] = __builtin_amdgcn_mfma_f32_16x16x32_bf16(a[m], b[n], acc[m][n], 0, 0, 0);
  };

  const int NT = DI / 32;                   // 24
  stage(0, 0);
  stage(1, 32);
  int bc = 0, bs = 2;
#pragma unroll 1
  for (int i = 0; i < NT - 1; ++i) {
    asm volatile("s_waitcnt vmcnt(4)" ::: "memory");
    __builtin_amdgcn_s_barrier();
    __builtin_amdgcn_sched_barrier(0);
    compute(bc);
    if (i + 2 < NT) stage(bs, (i + 2) * 32);
    bc = (bc == 2) ? 0 : bc + 1;
    bs = (bs == 2) ? 0 : bs + 1;
  }
  asm volatile("s_waitcnt vmcnt(0)" ::: "memory");
  __builtin_amdgcn_s_barrier();
  __builtin_amdgcn_sched_barrier(0);
  compute(bc);

  const unsigned short* L = lst + (size_t)e * NUM_T;
#pragma unroll
  for (int m = 0; m < 4; m++) {
#pragma unroll
    for (int r = 0; r < 4; r++) {
      int gr = m0 + wm * 64 + m * 16 + 4 * lgp + r;
      if (gr >= rcount) continue;
      unsigned short en = L[rs + gr];
      int t  = en & 0xFFF;
      int s  = (en >> 12) & 7;
      int tl = t - hf * TOK_HALF;
#pragma unroll
      for (int n = 0; n < 4; n++)
        slotbuf[((size_t)s * TOK_HALF + tl) * DH + n0 + wn * 64 + n * 16 + lr] =
            f2bf(acc[m][n][r]);
    }
  }
}

// ---- kernel 6: reduce 8 slots -> final fp32 output (one token half) -----

__global__ __launch_bounds__(256)
void reduce_half_k(const unsigned short* __restrict__ slotbuf,
                   float* __restrict__ outp, int hf) {
  size_t i  = (size_t)blockIdx.x * 256 + threadIdx.x;
  size_t tl = i >> 8;
  size_t h0 = (i & 255) * 8;
  float sum[8];
#pragma unroll
  for (int j = 0; j < 8; j++) sum[j] = 0.f;
#pragma unroll
  for (int s = 0; s < 8; s++) {
    short8 v = *(const short8*)(slotbuf + ((size_t)s * TOK_HALF + tl) * DH + h0);
#pragma unroll
    for (int j = 0; j < 8; j++) sum[j] += bf2f((unsigned short)v[j]);
  }
  float* o = outp + ((size_t)(hf * TOK_HALF) + tl) * DH + h0;
  float4 o0 = {sum[0], sum[1], sum[2], sum[3]};
  float4 o1 = {sum[4], sum[5], sum[6], sum[7]};
  *(float4*)o = o0;
  *(float4*)(o + 4) = o1;
}

// ---- launch --------------------------------------------------------------

extern "C" void kernel_launch(void* const* d_in, const int* in_sizes, int n_in,
                              void* d_out, int out_size, void* d_ws, size_t ws_size,
                              hipStream_t stream) {
  const float* x  = (const float*)d_in[0];   // [2,2048,2048]
  const float* wr = (const float*)d_in[1];   // [2048,16]
  const float* wg = (const float*)d_in[2];   // [16,2048,768]
  const float* wu = (const float*)d_in[3];   // [16,2048,768]
  const float* wd = (const float*)d_in[4];   // [16,768,2048]

  float* outF = (float*)d_out;               // final [T][H]
  float* outL = outF + FINAL_ELEMS;          // router logits [T][E]

  // workspace layout (bytes), total 180,682,880:
  //   hbf     @ 0          : 16,777,216   bf16 hidden [T][H]       (dead after gateup)
  //   wgubt   @ 16,777,216 : 100,663,296  bf16 stacked gate/up B^T [E][1536][H]
  //                                       rows j*128..+64 = gate[j*64..],
  //                                       +64..+128 = up[j*64..]  (dead after gateup)
  //   hsC     @ 117,440,512: 62,914,560   bf16 compacted h [E][2560][I]
  //   dwb     @ 180,355,072: 131,072      bf16 combine weights [T][E]
  //   lst     @ 180,486,144: 131,072      u16 lists [E][T]: t | slot<<12
  //   slt     @ 180,617,216: 65,536       u8 slot table [T][E]
  //   meta    @ 180,682,752: 128          i32 {half0_count, total} per expert
  //   slotbuf @ 0 (aliases hbf + wgubt[:50.3MB]): 67,108,864  bf16 [8][2048][H]
  //   wdbt    @ 67,108,864 (aliases wgubt tail): 50,331,648   bf16 dense [H][E*I]
  if (ws_size < 180682880ull) return;
  char* ws = (char*)d_ws;
  unsigned short* hbf   = (unsigned short*)(ws);
  unsigned short* wgubt = (unsigned short*)(ws + 16777216);
  unsigned short* hsC   = (unsigned short*)(ws + 117440512);
  unsigned short* dwb   = (unsigned short*)(ws + 180355072);
  unsigned short* lst   = (unsigned short*)(ws + 180486144);
  unsigned char*  slt   = (unsigned char*) (ws + 180617216);
  int*            meta  = (int*)           (ws + 180682752);
  unsigned short* sbuf  = (unsigned short*)(ws);             // after gateup
  unsigned short* wdbt  = (unsigned short*)(ws + 67108864);  // after gateup

  cvt_hidden_k<<<4096, 256, 0, stream>>>(x, hbf);
  // gate -> stacked rows (r>>6)*128 + (r&63); up -> +64
  transpose_cvt_k<<<dim3(24, 64, 16), dim3(32, 8), 0, stream>>>(
      wg, wgubt, 768, (long)2048 * 768, (long)1536 * 2048, 2048, 6, 128, 0);
  transpose_cvt_k<<<dim3(24, 64, 16), dim3(32, 8), 0, stream>>>(
      wu, wgubt, 768, (long)2048 * 768, (long)1536 * 2048, 2048, 6, 128, 64);
  router_k<<<4096, 256, 0, stream>>>(x, wr, outL, dwb, slt);
  build_lists_k<<<16, 256, 0, stream>>>(dwb, slt, lst, meta);
  gateup_k<<<1920, 256, 0, stream>>>(hbf, wgubt, dwb, lst, hsC);
  // wd -> dense wdbt [H][12288] (identity row map), written after gateup
  transpose_cvt_k<<<dim3(64, 24, 16), dim3(32, 8), 0, stream>>>(
      wd, wdbt, 2048, (long)768 * 2048, 768L, 12288, 11, 2048, 0);
  down_half_k<<<2560, 256, 0, stream>>>(hsC, wdbt, lst, meta, sbuf, 0);
  reduce_half_k<<<2048, 256, 0, stream>>>(sbuf, outF, 0);
  down_half_k<<<2560, 256, 0, stream>>>(hsC, wdbt, lst, meta, sbuf, 1);
  reduce_half_k<<<2048, 256, 0, stream>>>(sbuf, outF, 1);
}

// Round 8
// 655.415 us; speedup vs baseline: 1.1009x; 1.1009x over previous
//
#include <hip/hip_runtime.h>
#include <hip/hip_bf16.h>

// Qwen3 MoE sparse block, MI355X/gfx950.
// Shapes: T=4096 tokens (B2 x S2048), H=2048, I=768, E=16, top-k=8.
// Round 8: gateup = 8-wave (512-thr) 256x128 tile, BK=32, per-wave C 64x64,
// depth-2 counted-vmcnt(3) pipeline (3-buf LDS, 72KB -> 2 blocks/CU),
// TWO phases per K-tile each with own barrier + setprio MFMA cluster
// (producer/consumer wave alternation - the piece r7 lacked). Fragment and
// rotation-swizzle math unchanged (verified since r1). Epilogue exchange
// padded (stride 68) to kill r7's bank conflicts. Down path unchanged (r6).

typedef __attribute__((ext_vector_type(8))) short short8;   // 8 x bf16 (4 VGPRs) MFMA operand
typedef __attribute__((ext_vector_type(4))) float f32x4;    // MFMA accumulator

#define NUM_T 4096
#define DH    2048
#define DI    768
#define NE    16
#define DKD   (NE*DI)        // 12288 (dense wdbt row length)
#define HSC_CAP 2560         // compacted rows capacity per expert
#define TOK_HALF 2048
#define GU_NT (DH/32)        // 64 K-tiles in gateup
#define FINAL_ELEMS ((size_t)NUM_T*DH)

// ---- helpers -------------------------------------------------------------

static __device__ __forceinline__ unsigned short f2bf(float f) {
  unsigned int u = __builtin_bit_cast(unsigned int, f);
  u += 0x7fffu + ((u >> 16) & 1u);
  return (unsigned short)(u >> 16);
}

static __device__ __forceinline__ float bf2f(unsigned short b) {
  unsigned int u = ((unsigned int)b) << 16;
  return __builtin_bit_cast(float, u);
}

static __device__ __forceinline__ void gload16(const void* g, void* l) {
  __builtin_amdgcn_global_load_lds(
      (__attribute__((address_space(1))) void*)(g),
      (__attribute__((address_space(3))) void*)(l), 16, 0, 0);
}

// ---- kernel 1: hidden fp32 -> bf16 --------------------------------------

__global__ __launch_bounds__(256)
void cvt_hidden_k(const float* __restrict__ in, unsigned short* __restrict__ out) {
  size_t i = (size_t)blockIdx.x * 256 + threadIdx.x;
  const float4* p = (const float4*)in + i * 2;
  float4 a = p[0], b = p[1];
  short8 v;
  v[0] = (short)f2bf(a.x); v[1] = (short)f2bf(a.y);
  v[2] = (short)f2bf(a.z); v[3] = (short)f2bf(a.w);
  v[4] = (short)f2bf(b.x); v[5] = (short)f2bf(b.y);
  v[6] = (short)f2bf(b.z); v[7] = (short)f2bf(b.w);
  *(short8*)(out + i * 8) = v;
}

// ---- kernel 2: transpose + convert with output-row remap -----------------
// out row for original B^T row r: s = (r>>rShift)*rStrd + rOff + (r & mask).

__global__ __launch_bounds__(256)
void transpose_cvt_k(const float* __restrict__ in, unsigned short* __restrict__ out,
                     int C, long inStrideE, long outStrideE, int outLD,
                     int rShift, int rStrd, int rOff) {
  __shared__ float tile[32][33];
  const float* inE = in + (size_t)blockIdx.z * inStrideE;
  unsigned short* outE = out + (size_t)blockIdx.z * outStrideE;
  int c0 = blockIdx.x * 32, r0 = blockIdx.y * 32;
  int tx = threadIdx.x, ty = threadIdx.y;
#pragma unroll
  for (int i = 0; i < 4; i++)
    tile[ty * 4 + i][tx] = inE[(size_t)(r0 + ty * 4 + i) * C + c0 + tx];
  __syncthreads();
#pragma unroll
  for (int i = 0; i < 4; i++) {
    int c = ty * 4 + i;
    int r = c0 + c;
    int s = ((r >> rShift) * rStrd) + rOff + (r & ((1 << rShift) - 1));
    outE[(size_t)s * outLD + r0 + tx] = f2bf(tile[tx][c]);
  }
}

// ---- kernel 3: router + softmax + top-8 + renorm + slot assignment ------

__global__ __launch_bounds__(256)
void router_k(const float* __restrict__ x, const float* __restrict__ wr,
              float* __restrict__ logits_out, unsigned short* __restrict__ dwb,
              unsigned char* __restrict__ slt) {
  int t = blockIdx.x;
  int tid = threadIdx.x, lane = tid & 63, wid = tid >> 6;
  float acc[16];
#pragma unroll
  for (int e = 0; e < 16; e++) acc[e] = 0.f;
  const float* xt = x + (size_t)t * DH;
  for (int i = tid; i < DH; i += 256) {
    float hv = xt[i];
    const float4* w4 = (const float4*)(wr + (size_t)i * 16);
#pragma unroll
    for (int q = 0; q < 4; q++) {
      float4 w = w4[q];
      acc[q * 4 + 0] += hv * w.x; acc[q * 4 + 1] += hv * w.y;
      acc[q * 4 + 2] += hv * w.z; acc[q * 4 + 3] += hv * w.w;
    }
  }
#pragma unroll
  for (int e = 0; e < 16; e++) {
#pragma unroll
    for (int off = 32; off; off >>= 1) acc[e] += __shfl_xor(acc[e], off, 64);
  }
  __shared__ float red[4][16];
  if (lane == 0) {
#pragma unroll
    for (int e = 0; e < 16; e++) red[wid][e] = acc[e];
  }
  __syncthreads();
  if (tid == 0) {
    float lg[16];
#pragma unroll
    for (int e = 0; e < 16; e++) lg[e] = red[0][e] + red[1][e] + red[2][e] + red[3][e];
    float mx = lg[0];
#pragma unroll
    for (int e = 1; e < 16; e++) mx = fmaxf(mx, lg[e]);
    float p[16], s = 0.f;
#pragma unroll
    for (int e = 0; e < 16; e++) { p[e] = __expf(lg[e] - mx); s += p[e]; }
    float inv = 1.f / s;
#pragma unroll
    for (int e = 0; e < 16; e++) p[e] *= inv;
    float tmp[16];
#pragma unroll
    for (int e = 0; e < 16; e++) tmp[e] = p[e];
    int idx[8]; float val[8]; float ts = 0.f;
#pragma unroll
    for (int k = 0; k < 8; k++) {
      int b = 0; float bv = tmp[0];
#pragma unroll
      for (int e = 1; e < 16; e++) { if (tmp[e] > bv) { bv = tmp[e]; b = e; } }
      idx[k] = b; val[k] = bv; tmp[b] = -1.f; ts += bv;
    }
    float dw[16];
    unsigned char sl[16];
#pragma unroll
    for (int e = 0; e < 16; e++) { dw[e] = 0.f; sl[e] = 0xFF; }
    float invt = 1.f / ts;
#pragma unroll
    for (int k = 0; k < 8; k++) { dw[idx[k]] += val[k] * invt; sl[idx[k]] = (unsigned char)k; }
#pragma unroll
    for (int e = 0; e < 16; e++) {
      dwb[(size_t)t * 16 + e] = f2bf(dw[e]);
      slt[(size_t)t * 16 + e] = sl[e];
      logits_out[(size_t)t * 16 + e] = lg[e];
    }
  }
}

// ---- kernel 3b: per-expert compacted token lists + split metadata -------

__global__ __launch_bounds__(256)
void build_lists_k(const unsigned short* __restrict__ dwb,
                   const unsigned char* __restrict__ slt,
                   unsigned short* __restrict__ lst, int* __restrict__ meta) {
  int e = blockIdx.x;
  int tid = threadIdx.x;
  unsigned short loc[16]; int c = 0;
#pragma unroll
  for (int j = 0; j < 16; j++) {
    int t = tid * 16 + j;
    if (dwb[(size_t)t * 16 + e] != 0) {
      unsigned short s = slt[(size_t)t * 16 + e];
      loc[c++] = (unsigned short)(t | (s << 12));
    }
  }
  __shared__ int sc[256];
  __shared__ int pre[257];
  sc[tid] = c;
  __syncthreads();
  if (tid == 0) {
    int s = 0;
    for (int i = 0; i < 256; i++) { pre[i] = s; s += sc[i]; }
    pre[256] = s;
  }
  __syncthreads();
  unsigned short* L = lst + (size_t)e * NUM_T;
  int base = pre[tid];
  for (int j = 0; j < c; j++) L[base + j] = loc[j];
  int total = pre[256];
  for (int i = total + tid; i < NUM_T; i += 256) L[i] = 0xFFFFu;
  if (tid == 0) { meta[e * 2] = pre[128]; meta[e * 2 + 1] = total; }
}

// ---- kernel 4: gateup, 8-wave 2-phase deep pipeline ----------------------
// Tile 256 tokens x 128 stacked (gate64|up64), BK=32, 8 waves 4Mx2N,
// per-wave C = 64x64 (acc[4][4]). A/B 3-buf (72KB) -> 2 blocks/CU.
// vmcnt(3) at tile top (tile t+2 staged during t); 2 phases/tile each with
// own barrier + setprio 8-MFMA cluster (wave role alternation).

__global__ __launch_bounds__(512, 4)
void gateup_k(const unsigned short* __restrict__ hbf,
              const unsigned short* __restrict__ wgubt,
              const unsigned short* __restrict__ dwb,
              const unsigned short* __restrict__ lst,
              unsigned short* __restrict__ hsC) {
  // XCD-bijective swizzle: 1920 = 8 * 240; logical e-major -> n-tile -> m-tile
  const int bxr = blockIdx.x;
  const int wl  = (bxr & 7) * 240 + (bxr >> 3);
  const int e   = wl / 120;                 // 120 = 12 n-tiles * 10 m-tiles
  const int rem = wl - e * 120;
  const int j   = rem / 10;                 // stacked n-tile: cols j*64 (gate & up)
  const int m0  = (rem % 10) * 256;

  const unsigned short* L = lst + (size_t)e * NUM_T;
  if (L[m0] & 0x8000) return;               // tile fully beyond count[e]

  const int tid = threadIdx.x, lane = tid & 63, wid = tid >> 6;  // wid 0..7
  const int wm = wid >> 1, wn = wid & 1;    // 4M x 2N; wn=0 gate, wn=1 up
  const int lr = lane & 15, lgp = lane >> 4;

  __shared__ alignas(16) unsigned short ALDS[3 * 256 * 32];  // 48KB, 3-buf
  __shared__ alignas(16) unsigned short BLDS[3 * 128 * 32];  // 24KB, 3-buf

  f32x4 zero = {0.f, 0.f, 0.f, 0.f};
  f32x4 acc[4][4];
#pragma unroll
  for (int m = 0; m < 4; m++)
#pragma unroll
    for (int n = 0; n < 4; n++) acc[m][n] = zero;

  const unsigned short* wgubtE = wgubt + (size_t)e * 1536 * DH;

  const int srow    = lane >> 2;                                   // 0..15
  const int schunk8 = (((lane & 3) - ((lane >> 3) & 3)) & 3) * 8;  // inverse swizzle, src
  const int slot8   = (((lane >> 4) + ((lane >> 1) & 3)) & 3) * 8; // fragment read slot

  // A: 2 gload issues per tile; issue i covers token rows m0 + i*128 + wid*16 + srow
  const unsigned short* gA[2];
#pragma unroll
  for (int i = 0; i < 2; i++) {
    unsigned short en = L[m0 + i * 128 + wid * 16 + srow];
    size_t tok = (en & 0x8000) ? 0 : (size_t)(en & 0xFFF);
    gA[i] = hbf + tok * DH + schunk8;
  }
  // B: 1 gload issue per tile; stacked row j*128 + wid*16 + srow
  const unsigned short* gB = wgubtE + ((size_t)j * 128 + wid * 16 + srow) * DH + schunk8;

#define STAGE_A(buf, t, i) gload16(gA[i] + (size_t)(t) * 32, \
    ALDS + (buf) * 8192 + (i) * 4096 + wid * 512)
#define STAGE_B(buf, t) gload16(gB + (size_t)(t) * 32, \
    BLDS + (buf) * 4096 + wid * 512)
#define RD_A(mf) (*(const short8*)(Ab + (wm * 64 + (mf) * 16 + lr) * 32 + slot8))
#define RD_B(nf) (*(const short8*)(Bb + (wn * 64 + (nf) * 16 + lr) * 32 + slot8))

  // prologue: stage tiles 0 and 1 (3 issues each)
  STAGE_A(0, 0, 0); STAGE_A(0, 0, 1); STAGE_B(0, 0);
  STAGE_A(1, 1, 0); STAGE_A(1, 1, 1); STAGE_B(1, 1);

  int bc = 0, sb = 2;
  short8 a[4], b[4];
#pragma unroll 1
  for (int t = 0; t < GU_NT; ++t) {
    // tile-t data complete; newest 3 outstanding = tile t+1's stages
    if (t < GU_NT - 1) asm volatile("s_waitcnt vmcnt(3)" ::: "memory");
    else               asm volatile("s_waitcnt vmcnt(0)" ::: "memory");
    __builtin_amdgcn_s_barrier();
    __builtin_amdgcn_sched_barrier(0);
    const unsigned short* Ab = ALDS + bc * 8192;
    const unsigned short* Bb = BLDS + bc * 4096;
    // phase 0: stage A(t+2) || read a0-3, b0-1 || mfma mf0-3 x nf0-1
    if (t + 2 < GU_NT) { STAGE_A(sb, t + 2, 0); STAGE_A(sb, t + 2, 1); }
    a[0] = RD_A(0); a[1] = RD_A(1); a[2] = RD_A(2); a[3] = RD_A(3);
    b[0] = RD_B(0); b[1] = RD_B(1);
    asm volatile("s_waitcnt lgkmcnt(0)" ::: "memory");
    __builtin_amdgcn_sched_barrier(0);
    __builtin_amdgcn_s_setprio(1);
#pragma unroll
    for (int m = 0; m < 4; m++) {
      acc[m][0] = __builtin_amdgcn_mfma_f32_16x16x32_bf16(a[m], b[0], acc[m][0], 0, 0, 0);
      acc[m][1] = __builtin_amdgcn_mfma_f32_16x16x32_bf16(a[m], b[1], acc[m][1], 0, 0, 0);
    }
    __builtin_amdgcn_s_setprio(0);
    __builtin_amdgcn_s_barrier();
    // phase 1: stage B(t+2) || read b2-3 || mfma mf0-3 x nf2-3
    if (t + 2 < GU_NT) STAGE_B(sb, t + 2);
    b[2] = RD_B(2); b[3] = RD_B(3);
    asm volatile("s_waitcnt lgkmcnt(0)" ::: "memory");
    __builtin_amdgcn_sched_barrier(0);
    __builtin_amdgcn_s_setprio(1);
#pragma unroll
    for (int m = 0; m < 4; m++) {
      acc[m][2] = __builtin_amdgcn_mfma_f32_16x16x32_bf16(a[m], b[2], acc[m][2], 0, 0, 0);
      acc[m][3] = __builtin_amdgcn_mfma_f32_16x16x32_bf16(a[m], b[3], acc[m][3], 0, 0, 0);
    }
    __builtin_amdgcn_s_setprio(0);
    bc = (bc == 2) ? 0 : bc + 1;
    sb = (sb == 2) ? 0 : sb + 1;
  }
#undef STAGE_A
#undef STAGE_B
#undef RD_A
#undef RD_B

  // epilogue: up-waves (wn=1) publish C via padded LDS; gate-waves fuse
  __syncthreads();
  unsigned short* exch = (unsigned short*)ALDS;   // [4][64][68] = 34.8KB
  if (wn == 1) {
#pragma unroll
    for (int mf = 0; mf < 4; mf++)
#pragma unroll
      for (int nf = 0; nf < 4; nf++)
#pragma unroll
        for (int r = 0; r < 4; r++)
          exch[(wm * 64 + mf * 16 + lgp * 4 + r) * 68 + nf * 16 + lr]
              = f2bf(acc[mf][nf][r]);
  }
  __syncthreads();
  if (wn == 0) {
#pragma unroll
    for (int mf = 0; mf < 4; mf++) {
#pragma unroll
      for (int r = 0; r < 4; r++) {
        int m = wm * 64 + mf * 16 + lgp * 4 + r;
        unsigned short en = L[m0 + m];
        if (en & 0x8000) continue;
        int tp = en & 0xFFF;
        float w = bf2f(dwb[(size_t)tp * 16 + e]);
#pragma unroll
        for (int nf = 0; nf < 4; nf++) {
          float g = acc[mf][nf][r];
          float u = bf2f(exch[m * 68 + nf * 16 + lr]);
          float sig = 1.f / (1.f + __expf(-g));
          hsC[((size_t)e * HSC_CAP + m0 + m) * DI + j * 64 + nf * 16 + lr]
              = f2bf(sig * g * u * w);
        }
      }
    }
  }
}

// ---- kernel 5: per-expert down GEMM (half of tokens) -> slot buffer -----
// Unchanged from round 6 (3-stage counted-vmcnt pipeline).

__global__ __launch_bounds__(256, 3)
void down_half_k(const unsigned short* __restrict__ hsC,
                 const unsigned short* __restrict__ wdbt,
                 const unsigned short* __restrict__ lst,
                 const int* __restrict__ meta,
                 unsigned short* __restrict__ slotbuf, int hf) {
  const int bxr = blockIdx.x;
  const int wl  = (bxr & 7) * 320 + (bxr >> 3);
  const int e   = wl / 160;
  const int rem = wl - e * 160;
  const int n0  = (rem / 10) * 128;
  const int m0  = (rem % 10) * 128;

  const int rs = hf ? meta[e * 2] : 0;
  const int re = hf ? meta[e * 2 + 1] : meta[e * 2];
  const int rcount = re - rs;
  if (m0 >= rcount) return;

  const int tid = threadIdx.x, lane = tid & 63, wid = tid >> 6;
  const int wm = wid >> 1, wn = wid & 1;
  const int lr = lane & 15, lgp = lane >> 4;

  __shared__ alignas(16) unsigned short As[3 * 128 * 32];
  __shared__ alignas(16) unsigned short Bs[3 * 128 * 32];

  f32x4 zero = {0.f, 0.f, 0.f, 0.f};
  f32x4 acc[4][4];
#pragma unroll
  for (int m = 0; m < 4; m++)
#pragma unroll
    for (int n = 0; n < 4; n++) acc[m][n] = zero;

  const int srow    = lane >> 2;
  const int schunk8 = (((lane & 3) - ((lane >> 3) & 3)) & 3) * 8;
  const int sOff0   = wid * 1024;
  const int sOff1   = sOff0 + 512;
  const size_t arow0 = (size_t)(e * HSC_CAP + rs + m0 + wid * 32 + srow);
  const size_t arow1 = arow0 + 16;
  const size_t brow0 = (size_t)(n0 + wid * 32 + srow), brow1 = brow0 + 16;
  const int slot8 = (((lane >> 4) + ((lane >> 1) & 3)) & 3) * 8;

  const unsigned short* wdE = wdbt + (size_t)e * DI;

  auto stage = [&](int b, int k0) {
    unsigned short* Ab = As + b * 4096;
    unsigned short* Bb = Bs + b * 4096;
    gload16(hsC + arow0 * DI + k0 + schunk8, Ab + sOff0);
    gload16(hsC + arow1 * DI + k0 + schunk8, Ab + sOff1);
    gload16(wdE + brow0 * DKD + k0 + schunk8, Bb + sOff0);
    gload16(wdE + brow1 * DKD + k0 + schunk8, Bb + sOff1);
  };

  auto compute = [&](int bsel) {
    const unsigned short* Ab = As + bsel * 4096;
    const unsigned short* Bb = Bs + bsel * 4096;
    short8 a[4], b[4];
#pragma unroll
    for (int m = 0; m < 4; m++)
      a[m] = *(const short8*)(Ab + (size_t)(wm * 64 + m * 16 + lr) * 32 + slot8);
#pragma unroll
    for (int n = 0; n < 4; n++)
      b[n] = *(const short8*)(Bs + bsel * 4096 + (size_t)(wn * 64 + n * 16 + lr) * 32 + slot8);
#pragma unroll
    for (int m = 0; m < 4; m++)
#pragma unroll
      for (int n = 0; n < 4; n++)
        acc[m][n] = __builtin_amdgcn_mfma_f32_16x16x32_bf16(a[m], b[n], acc[m][n], 0, 0, 0);
    (void)Bb;
  };

  const int NT = DI / 32;                   // 24
  stage(0, 0);
  stage(1, 32);
  int bc = 0, bs = 2;
#pragma unroll 1
  for (int i = 0; i < NT - 1; ++i) {
    asm volatile("s_waitcnt vmcnt(4)" ::: "memory");
    __builtin_amdgcn_s_barrier();
    __builtin_amdgcn_sched_barrier(0);
    compute(bc);
    if (i + 2 < NT) stage(bs, (i + 2) * 32);
    bc = (bc == 2) ? 0 : bc + 1;
    bs = (bs == 2) ? 0 : bs + 1;
  }
  asm volatile("s_waitcnt vmcnt(0)" ::: "memory");
  __builtin_amdgcn_s_barrier();
  __builtin_amdgcn_sched_barrier(0);
  compute(bc);

  const unsigned short* L = lst + (size_t)e * NUM_T;
#pragma unroll
  for (int m = 0; m < 4; m++) {
#pragma unroll
    for (int r = 0; r < 4; r++) {
      int gr = m0 + wm * 64 + m * 16 + 4 * lgp + r;
      if (gr >= rcount) continue;
      unsigned short en = L[rs + gr];
      int t  = en & 0xFFF;
      int s  = (en >> 12) & 7;
      int tl = t - hf * TOK_HALF;
#pragma unroll
      for (int n = 0; n < 4; n++)
        slotbuf[((size_t)s * TOK_HALF + tl) * DH + n0 + wn * 64 + n * 16 + lr] =
            f2bf(acc[m][n][r]);
    }
  }
}

// ---- kernel 6: reduce 8 slots -> final fp32 output (one token half) -----

__global__ __launch_bounds__(256)
void reduce_half_k(const unsigned short* __restrict__ slotbuf,
                   float* __restrict__ outp, int hf) {
  size_t i  = (size_t)blockIdx.x * 256 + threadIdx.x;
  size_t tl = i >> 8;
  size_t h0 = (i & 255) * 8;
  float sum[8];
#pragma unroll
  for (int j = 0; j < 8; j++) sum[j] = 0.f;
#pragma unroll
  for (int s = 0; s < 8; s++) {
    short8 v = *(const short8*)(slotbuf + ((size_t)s * TOK_HALF + tl) * DH + h0);
#pragma unroll
    for (int j = 0; j < 8; j++) sum[j] += bf2f((unsigned short)v[j]);
  }
  float* o = outp + ((size_t)(hf * TOK_HALF) + tl) * DH + h0;
  float4 o0 = {sum[0], sum[1], sum[2], sum[3]};
  float4 o1 = {sum[4], sum[5], sum[6], sum[7]};
  *(float4*)o = o0;
  *(float4*)(o + 4) = o1;
}

// ---- launch --------------------------------------------------------------

extern "C" void kernel_launch(void* const* d_in, const int* in_sizes, int n_in,
                              void* d_out, int out_size, void* d_ws, size_t ws_size,
                              hipStream_t stream) {
  const float* x  = (const float*)d_in[0];   // [2,2048,2048]
  const float* wr = (const float*)d_in[1];   // [2048,16]
  const float* wg = (const float*)d_in[2];   // [16,2048,768]
  const float* wu = (const float*)d_in[3];   // [16,2048,768]
  const float* wd = (const float*)d_in[4];   // [16,768,2048]

  float* outF = (float*)d_out;               // final [T][H]
  float* outL = outF + FINAL_ELEMS;          // router logits [T][E]

  // workspace layout (bytes), total 180,682,880 (same as r7):
  //   hbf     @ 0          : 16,777,216   bf16 hidden [T][H]       (dead after gateup)
  //   wgubt   @ 16,777,216 : 100,663,296  bf16 stacked gate/up B^T [E][1536][H]
  //   hsC     @ 117,440,512: 62,914,560   bf16 compacted h [E][2560][I]
  //   dwb     @ 180,355,072: 131,072      bf16 combine weights [T][E]
  //   lst     @ 180,486,144: 131,072      u16 lists [E][T]: t | slot<<12
  //   slt     @ 180,617,216: 65,536       u8 slot table [T][E]
  //   meta    @ 180,682,752: 128          i32 {half0_count, total} per expert
  //   slotbuf @ 0 (aliases hbf + wgubt head): 67,108,864  bf16 [8][2048][H]
  //   wdbt    @ 67,108,864 (aliases wgubt tail): 50,331,648  bf16 dense [H][E*I]
  if (ws_size < 180682880ull) return;
  char* ws = (char*)d_ws;
  unsigned short* hbf   = (unsigned short*)(ws);
  unsigned short* wgubt = (unsigned short*)(ws + 16777216);
  unsigned short* hsC   = (unsigned short*)(ws + 117440512);
  unsigned short* dwb   = (unsigned short*)(ws + 180355072);
  unsigned short* lst   = (unsigned short*)(ws + 180486144);
  unsigned char*  slt   = (unsigned char*) (ws + 180617216);
  int*            meta  = (int*)           (ws + 180682752);
  unsigned short* sbuf  = (unsigned short*)(ws);             // after gateup
  unsigned short* wdbt  = (unsigned short*)(ws + 67108864);  // after gateup

  cvt_hidden_k<<<4096, 256, 0, stream>>>(x, hbf);
  // gate -> stacked rows (r>>6)*128 + (r&63); up -> +64
  transpose_cvt_k<<<dim3(24, 64, 16), dim3(32, 8), 0, stream>>>(
      wg, wgubt, 768, (long)2048 * 768, (long)1536 * 2048, 2048, 6, 128, 0);
  transpose_cvt_k<<<dim3(24, 64, 16), dim3(32, 8), 0, stream>>>(
      wu, wgubt, 768, (long)2048 * 768, (long)1536 * 2048, 2048, 6, 128, 64);
  router_k<<<4096, 256, 0, stream>>>(x, wr, outL, dwb, slt);
  build_lists_k<<<16, 256, 0, stream>>>(dwb, slt, lst, meta);
  gateup_k<<<1920, 512, 0, stream>>>(hbf, wgubt, dwb, lst, hsC);
  // wd -> dense wdbt [H][12288] (identity row map), written after gateup
  transpose_cvt_k<<<dim3(64, 24, 16), dim3(32, 8), 0, stream>>>(
      wd, wdbt, 2048, (long)768 * 2048, 768L, 12288, 11, 2048, 0);
  down_half_k<<<2560, 256, 0, stream>>>(hsC, wdbt, lst, meta, sbuf, 0);
  reduce_half_k<<<2048, 256, 0, stream>>>(sbuf, outF, 0);
  down_half_k<<<2560, 256, 0, stream>>>(hsC, wdbt, lst, meta, sbuf, 1);
  reduce_half_k<<<2048, 256, 0, stream>>>(sbuf, outF, 1);
}